// Round 7
// baseline (115.770 us; speedup 1.0000x reference)
//
#include <hip/hip_runtime.h>
#include <hip/hip_bf16.h>

// Problem constants (from reference)
#define NUM_NEURONS 32768
#define INPUT_SIZE  8192
#define BATCH       512

typedef float f32x4 __attribute__((ext_vector_type(4)));

// ---------------------------------------------------------------------------
// Fused kernel: per-block
//   1. compute this chunk's 4 affine coefficients from gate_weights
//      (every logic op is affine in {1,a,b,ab}: out = C0 + Ca*a + Cb*b + Cab*ab)
//   2. pipelined row loop: double-buffered LDS staging of x rows via
//      global_load_lds, counted vmcnt (stores stay in flight), raw s_barrier.
// ---------------------------------------------------------------------------
constexpr int CHUNK  = 2048;                  // neurons per block
constexpr int NPT    = CHUNK / 256;           // 8 per thread
constexpr int NGRP   = NPT / 4;               // 2 float4-store groups
constexpr int RPB    = 8;                     // rows per block
constexpr int XF4    = INPUT_SIZE / 4 / 256;  // 8 stage iterations (16B/lane)
constexpr int NCHUNKS = NUM_NEURONS / CHUNK;          // 16
constexpr int NROWG   = BATCH / RPB;                  // 64
constexpr int NXCD    = 8;

__global__ __launch_bounds__(256) void logic_main_kernel(
    const float* __restrict__ x,
    const float* __restrict__ gw,
    const int4*  __restrict__ idx4,
    float*       __restrict__ out)
{
    __shared__ float sx[2][INPUT_SIZE];       // 2 x 32 KiB double buffer

    const int tid = threadIdx.x;

    // XCD-aware swizzle: bid%8 = native XCD round-robin. Each XCD owns
    // 8 row-groups x all 16 chunks -> 2 MiB x working set in its 4 MiB L2.
    const int bid    = blockIdx.x;
    const int xcd    = bid & (NXCD - 1);
    const int within = bid >> 3;                          // 0..127
    const int chunkI = within & (NCHUNKS - 1);            // 0..15
    const int rowgI  = xcd * (NROWG / NXCD) + (within >> 4);  // 0..63
    const int chunk0 = chunkI * CHUNK;
    const int row0   = rowgI * RPB;

    // ---- Issue stage of row0 into buffer 0 immediately (hide under coeffs).
    auto stage = [&](int buf, int row) {
        const float4* xrow = reinterpret_cast<const float4*>(x + (size_t)row * INPUT_SIZE);
        float4* s4 = reinterpret_cast<float4*>(sx[buf]);
#pragma unroll
        for (int i = 0; i < XF4; ++i) {
            __builtin_amdgcn_global_load_lds(
                (const __attribute__((address_space(1))) void*)(xrow + i * 256 + tid),
                (__attribute__((address_space(3))) void*)(s4 + i * 256 + tid),
                16, 0, 0);
        }
    };
    stage(0, row0);

    // ---- Fused coefficient computation (was kernel A). Group g covers
    // neurons n = chunk0 + g*1024 + tid*4 + j, j=0..3.
    float4 c[NPT];
    int2   id[NPT];
#pragma unroll
    for (int g = 0; g < NGRP; ++g) {
        const int nbase = chunk0 + g * 1024 + tid * 4;
        const int4 p0 = idx4[(nbase >> 1) + 0];
        const int4 p1 = idx4[(nbase >> 1) + 1];
        id[g*4+0] = make_int2(p0.x, p0.y);
        id[g*4+1] = make_int2(p0.z, p0.w);
        id[g*4+2] = make_int2(p1.x, p1.y);
        id[g*4+3] = make_int2(p1.z, p1.w);
#pragma unroll
        for (int j = 0; j < 4; ++j) {
            const float* gg = gw + (size_t)(nbase + j) * 16;
            float w[16];
#pragma unroll
            for (int i = 0; i < 16; i += 4) {
                float4 v = *reinterpret_cast<const float4*>(gg + i);
                w[i+0] = v.x; w[i+1] = v.y; w[i+2] = v.z; w[i+3] = v.w;
            }
            // gate weights ~ N(0,1): no max-subtraction needed for exp range
            float s = 0.f;
#pragma unroll
            for (int i = 0; i < 16; ++i) { w[i] = __expf(w[i]); s += w[i]; }
            const float inv = 1.0f / s;
            const float C0  = (w[8] + w[9] + w[10] + w[11] + w[12] + w[13] + w[14] + w[15]) * inv;
            const float Ca  = (w[2] + w[3] + w[6] + w[7] - w[8] - w[9] - w[12] - w[13]) * inv;
            const float Cb  = (w[4] + w[5] + w[6] + w[7] - w[8] - w[9] - w[10] - w[11]) * inv;
            const float Cab = (w[1] - w[2] - w[4] - 2.f*w[6] - w[7]
                               + w[8] + 2.f*w[9] + w[11] + w[13] - w[14]) * inv;
            c[g*4+j] = make_float4(C0, Ca, Cb, Cab);
        }
    }

    // ---- Wait for row0 staging, sync all waves.
    asm volatile("s_waitcnt vmcnt(0)" ::: "memory");
    __builtin_amdgcn_s_barrier();

    // ---- Pipelined row loop. Per iteration (fully unrolled, cur is static):
    //   issue stage(r+1) -> fence -> gather/FMA/store row r -> vmcnt(2)+barrier
    // vmcnt(2): the 2 newest outstanding VMEM ops are this iter's stores
    // (issued after the 8 stage loads); waiting to <=2 guarantees the stage
    // loads have landed while leaving the stores in flight. Stores are never
    // drained inside the loop.
#pragma unroll
    for (int r = 0; r < RPB; ++r) {
        const int cur = r & 1;
        if (r + 1 < RPB) stage(cur ^ 1, row0 + r + 1);
        asm volatile("" ::: "memory");        // pin stage-before-store order

        const int row = row0 + r;
        f32x4* o = reinterpret_cast<f32x4*>(out + (size_t)row * NUM_NEURONS + chunk0);
#pragma unroll
        for (int g = 0; g < NGRP; ++g) {
            f32x4 res;
#pragma unroll
            for (int j = 0; j < 4; ++j) {
                const float4 cc = c[g*4+j];
                const float a = sx[cur][id[g*4+j].x];
                const float b = sx[cur][id[g*4+j].y];
                res[j] = fmaf(a, fmaf(cc.w, b, cc.y), fmaf(cc.z, b, cc.x));
            }
            __builtin_nontemporal_store(res, o + g * 256 + tid);
        }

        if (r + 1 < RPB) {
            asm volatile("s_waitcnt vmcnt(2)" ::: "memory");
            __builtin_amdgcn_s_barrier();
        }
    }
}

extern "C" void kernel_launch(void* const* d_in, const int* in_sizes, int n_in,
                              void* d_out, int out_size, void* d_ws, size_t ws_size,
                              hipStream_t stream)
{
    const float* x   = (const float*)d_in[0];   // (512, 8192) f32
    const float* gw  = (const float*)d_in[1];   // (32768, 16) f32
    const int4*  idx = (const int4*)d_in[2];    // (32768, 2) i32, int4 pairs
    float* out = (float*)d_out;                 // (512, 32768) f32

    const int nblocks = NCHUNKS * NROWG;        // 1024
    logic_main_kernel<<<nblocks, 256, 0, stream>>>(x, gw, idx, out);
}

// Round 8
// 94.776 us; speedup vs baseline: 1.2215x; 1.2215x over previous
//
#include <hip/hip_runtime.h>
#include <hip/hip_bf16.h>

// Problem constants (from reference)
#define NUM_NEURONS 32768
#define INPUT_SIZE  8192
#define BATCH       512

typedef float f32x4 __attribute__((ext_vector_type(4)));

// ---------------------------------------------------------------------------
// Kernel A: per-neuron softmax over 16 gate weights -> 4 affine coefficients.
// Every logic op is affine in {1, a, b, ab}: out = C0 + Ca*a + Cb*b + Cab*a*b
// Coeffs land in d_ws (512 KiB), L2/L3-resident for kernel B.
// ---------------------------------------------------------------------------
__global__ __launch_bounds__(256) void logic_coeff_kernel(
    const float* __restrict__ gw, float4* __restrict__ coeffs)
{
    const int n = blockIdx.x * 256 + threadIdx.x;
    if (n >= NUM_NEURONS) return;
    const float* g = gw + (size_t)n * 16;

    float w[16];
#pragma unroll
    for (int i = 0; i < 16; i += 4) {
        float4 v = *reinterpret_cast<const float4*>(g + i);
        w[i+0] = v.x; w[i+1] = v.y; w[i+2] = v.z; w[i+3] = v.w;
    }
    float m = w[0];
#pragma unroll
    for (int i = 1; i < 16; ++i) m = fmaxf(m, w[i]);
    float s = 0.f;
#pragma unroll
    for (int i = 0; i < 16; ++i) { w[i] = __expf(w[i] - m); s += w[i]; }
    const float inv = 1.0f / s;

    const float C0  = (w[8] + w[9] + w[10] + w[11] + w[12] + w[13] + w[14] + w[15]) * inv;
    const float Ca  = (w[2] + w[3] + w[6] + w[7] - w[8] - w[9] - w[12] - w[13]) * inv;
    const float Cb  = (w[4] + w[5] + w[6] + w[7] - w[8] - w[9] - w[10] - w[11]) * inv;
    const float Cab = (w[1] - w[2] - w[4] - 2.f*w[6] - w[7]
                       + w[8] + 2.f*w[9] + w[11] + w[13] - w[14]) * inv;

    coeffs[n] = make_float4(C0, Ca, Cb, Cab);
}

// ---------------------------------------------------------------------------
// Kernel B: one block = one ROW-PAIR x ALL neurons. 1024 threads (16 waves),
// grid=256 -> exactly 1 block/CU, 32 waves... 16 waves/CU. Structure:
//   - stage rows (2b, 2b+1) = contiguous 64 KiB of x via global_load_lds(16B)
//     -> x staged exactly once globally (zero redundancy)
//   - ONE barrier
//   - barrier-free streaming loop over 8 neuron-quads: coeff+idx from L2,
//     16 random LDS gathers, FMA, 2 nontemporal f32x4 stores.
// All waves independent after the barrier -> store/LDS/L2 floors overlap.
// ---------------------------------------------------------------------------
constexpr int RPB = 2;                              // rows per block
constexpr int BLK = 1024;                           // threads per block
constexpr int QPT = NUM_NEURONS / 4 / BLK;          // 8 neuron-quads per thread
constexpr int SF4 = RPB * INPUT_SIZE / 4 / BLK;     // 4 stage loads per thread

__global__ __launch_bounds__(BLK, 4) void logic_main_kernel(
    const float*  __restrict__ x,
    const float4* __restrict__ coeffs,
    const int4*   __restrict__ idx4,
    float*        __restrict__ out)
{
    __shared__ float sx[RPB][INPUT_SIZE];           // 64 KiB

    const int tid  = threadIdx.x;
    const int row0 = blockIdx.x * RPB;

    // Stage both rows (contiguous in x) via async global->LDS, 16 B/lane.
    {
        const float4* xr = reinterpret_cast<const float4*>(x + (size_t)row0 * INPUT_SIZE);
        float4* s4 = reinterpret_cast<float4*>(&sx[0][0]);
#pragma unroll
        for (int i = 0; i < SF4; ++i) {
            __builtin_amdgcn_global_load_lds(
                (const __attribute__((address_space(1))) void*)(xr + i * BLK + tid),
                (__attribute__((address_space(3))) void*)(s4 + i * BLK + tid),
                16, 0, 0);
        }
    }
    asm volatile("s_waitcnt vmcnt(0)" ::: "memory");
    __builtin_amdgcn_s_barrier();                   // the ONLY barrier

    // Streaming loop: no syncs, compiler free to pipeline loads ahead.
#pragma unroll 2
    for (int g = 0; g < QPT; ++g) {
        const int nb = g * (BLK * 4) + tid * 4;     // neuron quad base

        const float4 c0 = coeffs[nb + 0];
        const float4 c1 = coeffs[nb + 1];
        const float4 c2 = coeffs[nb + 2];
        const float4 c3 = coeffs[nb + 3];
        const int4   p0 = idx4[(nb >> 1) + 0];      // (i0,i1) for neurons 0,1
        const int4   p1 = idx4[(nb >> 1) + 1];      // (i0,i1) for neurons 2,3

#pragma unroll
        for (int rr = 0; rr < RPB; ++rr) {
            const float* s = sx[rr];
            f32x4 res;
            {
                const float a = s[p0.x], b = s[p0.y];
                res[0] = fmaf(a, fmaf(c0.w, b, c0.y), fmaf(c0.z, b, c0.x));
            }
            {
                const float a = s[p0.z], b = s[p0.w];
                res[1] = fmaf(a, fmaf(c1.w, b, c1.y), fmaf(c1.z, b, c1.x));
            }
            {
                const float a = s[p1.x], b = s[p1.y];
                res[2] = fmaf(a, fmaf(c2.w, b, c2.y), fmaf(c2.z, b, c2.x));
            }
            {
                const float a = s[p1.z], b = s[p1.w];
                res[3] = fmaf(a, fmaf(c3.w, b, c3.y), fmaf(c3.z, b, c3.x));
            }
            __builtin_nontemporal_store(
                res, reinterpret_cast<f32x4*>(out + (size_t)(row0 + rr) * NUM_NEURONS + nb));
        }
    }
}

extern "C" void kernel_launch(void* const* d_in, const int* in_sizes, int n_in,
                              void* d_out, int out_size, void* d_ws, size_t ws_size,
                              hipStream_t stream)
{
    const float* x   = (const float*)d_in[0];   // (512, 8192) f32
    const float* gw  = (const float*)d_in[1];   // (32768, 16) f32
    const int4*  idx = (const int4*)d_in[2];    // (32768, 2) i32, int4 pairs
    float* out = (float*)d_out;                 // (512, 32768) f32

    float4* coeffs = (float4*)d_ws;             // 512 KiB scratch

    logic_coeff_kernel<<<NUM_NEURONS / 256, 256, 0, stream>>>(gw, coeffs);

    logic_main_kernel<<<BATCH / RPB, BLK, 0, stream>>>(x, coeffs, idx, out);
}

// Round 10
// 92.450 us; speedup vs baseline: 1.2522x; 1.0252x over previous
//
#include <hip/hip_runtime.h>
#include <hip/hip_bf16.h>

// Problem constants (from reference)
#define NUM_NEURONS 32768
#define INPUT_SIZE  8192
#define BATCH       512

typedef float f32x4 __attribute__((ext_vector_type(4)));

// ---------------------------------------------------------------------------
// Kernel A: per-neuron softmax over 16 gate weights -> 4 affine coefficients.
// Every logic op is affine in {1, a, b, ab}: out = C0 + Ca*a + Cb*b + Cab*a*b
// Coeffs land in d_ws (512 KiB) with REGULAR stores (want them L2-resident).
// ---------------------------------------------------------------------------
__global__ __launch_bounds__(256) void logic_coeff_kernel(
    const float* __restrict__ gw, float4* __restrict__ coeffs)
{
    const int n = blockIdx.x * 256 + threadIdx.x;
    if (n >= NUM_NEURONS) return;
    const float* g = gw + (size_t)n * 16;

    float w[16];
#pragma unroll
    for (int i = 0; i < 16; i += 4) {
        float4 v = *reinterpret_cast<const float4*>(g + i);
        w[i+0] = v.x; w[i+1] = v.y; w[i+2] = v.z; w[i+3] = v.w;
    }
    float m = w[0];
#pragma unroll
    for (int i = 1; i < 16; ++i) m = fmaxf(m, w[i]);
    float s = 0.f;
#pragma unroll
    for (int i = 0; i < 16; ++i) { w[i] = __expf(w[i] - m); s += w[i]; }
    const float inv = 1.0f / s;

    const float C0  = (w[8] + w[9] + w[10] + w[11] + w[12] + w[13] + w[14] + w[15]) * inv;
    const float Ca  = (w[2] + w[3] + w[6] + w[7] - w[8] - w[9] - w[12] - w[13]) * inv;
    const float Cb  = (w[4] + w[5] + w[6] + w[7] - w[8] - w[9] - w[10] - w[11]) * inv;
    const float Cab = (w[1] - w[2] - w[4] - 2.f*w[6] - w[7]
                       + w[8] + 2.f*w[9] + w[11] + w[13] - w[14]) * inv;

    coeffs[n] = make_float4(C0, Ca, Cb, Cab);
}

// ---------------------------------------------------------------------------
// Kernel B: block = (row-pair, neuron-half). 512 threads (8 waves), 64 KiB
// LDS -> 2 independent blocks/CU (one's load phase overlaps the other's
// gather/store phase). One barrier per block, then a barrier-free streaming
// loop with WAVE-PHASE STAGGER: at iteration it, wave w handles neuron slab
// (it+w)&7 at sub-offset w*256 -> waves are always in different pipe phases.
//   bid layout: rp = bid & 255 (row-pair), half = bid >> 8. Blocks bid and
//   bid+256 map to the same XCD (256%8==0), so the re-staged x rows are
//   L2 hits for the second half-block.
// ---------------------------------------------------------------------------
constexpr int BLK  = 512;                        // threads per block
constexpr int RPB  = 2;                          // rows per block
constexpr int HALF = NUM_NEURONS / 2;            // 16384 neurons per block
constexpr int QPT  = HALF / 4 / BLK;             // 8 quad-iterations per thread
constexpr int SF4  = RPB * INPUT_SIZE / 4 / BLK; // 8 stage loads per thread

__global__ __launch_bounds__(BLK, 4) void logic_main_kernel(
    const float*  __restrict__ x,
    const float4* __restrict__ coeffs,
    const int4*   __restrict__ idx4,
    float*        __restrict__ out)
{
    __shared__ float sx[RPB][INPUT_SIZE];        // 64 KiB

    const int tid  = threadIdx.x;
    const int bid  = blockIdx.x;
    const int rp   = bid & 255;                  // row-pair index
    const int half = bid >> 8;                   // 0 / 1
    const int row0 = rp * RPB;
    const int nh0  = half * HALF;                // neuron-half base

    // ---- Stage both rows (contiguous 64 KiB of x) via global_load_lds.
    {
        const float4* xr = reinterpret_cast<const float4*>(x + (size_t)row0 * INPUT_SIZE);
        float4* s4 = reinterpret_cast<float4*>(&sx[0][0]);
#pragma unroll
        for (int i = 0; i < SF4; ++i) {
            __builtin_amdgcn_global_load_lds(
                (const __attribute__((address_space(1))) void*)(xr + i * BLK + tid),
                (__attribute__((address_space(3))) void*)(s4 + i * BLK + tid),
                16, 0, 0);
        }
    }
    asm volatile("s_waitcnt vmcnt(0)" ::: "memory");
    __builtin_amdgcn_s_barrier();                // the ONLY barrier

    const int wid  = tid >> 6;                   // wave id 0..7
    const int lane = tid & 63;

    float* o0 = out + (size_t)row0 * NUM_NEURONS;
    float* o1 = o0 + NUM_NEURONS;

    // ---- Barrier-free streaming loop, wave-staggered slabs.
#pragma unroll 2
    for (int it = 0; it < QPT; ++it) {
        const int g  = (it + wid) & (QPT - 1);   // slab for this wave
        const int nb = nh0 + g * 2048 + wid * 256 + lane * 4;  // quad base

        const float4 c0 = coeffs[nb + 0];
        const float4 c1 = coeffs[nb + 1];
        const float4 c2 = coeffs[nb + 2];
        const float4 c3 = coeffs[nb + 3];
        const int4   p0 = idx4[(nb >> 1) + 0];   // (i0,i1) neurons 0,1
        const int4   p1 = idx4[(nb >> 1) + 1];   // (i0,i1) neurons 2,3

        {
            const float* s = sx[0];
            f32x4 res;
            { const float a = s[p0.x], b = s[p0.y];
              res[0] = fmaf(a, fmaf(c0.w, b, c0.y), fmaf(c0.z, b, c0.x)); }
            { const float a = s[p0.z], b = s[p0.w];
              res[1] = fmaf(a, fmaf(c1.w, b, c1.y), fmaf(c1.z, b, c1.x)); }
            { const float a = s[p1.x], b = s[p1.y];
              res[2] = fmaf(a, fmaf(c2.w, b, c2.y), fmaf(c2.z, b, c2.x)); }
            { const float a = s[p1.z], b = s[p1.w];
              res[3] = fmaf(a, fmaf(c3.w, b, c3.y), fmaf(c3.z, b, c3.x)); }
            __builtin_nontemporal_store(res, reinterpret_cast<f32x4*>(o0 + nb));
        }
        {
            const float* s = sx[1];
            f32x4 res;
            { const float a = s[p0.x], b = s[p0.y];
              res[0] = fmaf(a, fmaf(c0.w, b, c0.y), fmaf(c0.z, b, c0.x)); }
            { const float a = s[p0.z], b = s[p0.w];
              res[1] = fmaf(a, fmaf(c1.w, b, c1.y), fmaf(c1.z, b, c1.x)); }
            { const float a = s[p1.x], b = s[p1.y];
              res[2] = fmaf(a, fmaf(c2.w, b, c2.y), fmaf(c2.z, b, c2.x)); }
            { const float a = s[p1.z], b = s[p1.w];
              res[3] = fmaf(a, fmaf(c3.w, b, c3.y), fmaf(c3.z, b, c3.x)); }
            __builtin_nontemporal_store(res, reinterpret_cast<f32x4*>(o1 + nb));
        }
    }
}

extern "C" void kernel_launch(void* const* d_in, const int* in_sizes, int n_in,
                              void* d_out, int out_size, void* d_ws, size_t ws_size,
                              hipStream_t stream)
{
    const float* x   = (const float*)d_in[0];   // (512, 8192) f32
    const float* gw  = (const float*)d_in[1];   // (32768, 16) f32
    const int4*  idx = (const int4*)d_in[2];    // (32768, 2) i32, int4 pairs
    float* out = (float*)d_out;                 // (512, 32768) f32

    float4* coeffs = (float4*)d_ws;             // 512 KiB scratch

    logic_coeff_kernel<<<NUM_NEURONS / 256, 256, 0, stream>>>(gw, coeffs);

    // 256 row-pairs x 2 neuron-halves
    logic_main_kernel<<<(BATCH / RPB) * 2, BLK, 0, stream>>>(x, coeffs, idx, out);
}